// Round 4
// baseline (211.057 us; speedup 1.0000x reference)
//
#include <hip/hip_runtime.h>

typedef unsigned short u16;
typedef __attribute__((ext_vector_type(8))) short bf16x8;
typedef __attribute__((ext_vector_type(4))) float f32x4;
typedef __attribute__((ext_vector_type(4))) unsigned int u32x4;

#define SEQ 2048
#define HID 1024
#define NHEAD 16
#define HDIM 64
#define MTOK 4096  // B*S

#define MFMA16(a,b,c) __builtin_amdgcn_mfma_f32_16x16x32_bf16(a,b,c,0,0,0)

__device__ __forceinline__ u16 f2bf(float f){
  unsigned int u = __builtin_bit_cast(unsigned int, f);
  u += 0x7fffu + ((u >> 16) & 1u);
  return (u16)(u >> 16);
}

__device__ __forceinline__ void gload16(const u16* g, u16* l){
  __builtin_amdgcn_global_load_lds((const __attribute__((address_space(1))) void*)g,
                                   (__attribute__((address_space(3))) void*)l, 16, 0, 0);
}

// ---------------- cast fp32 -> bf16, 8 elems/thread ----------------
__global__ __launch_bounds__(256) void cast_f32_bf16(const float* __restrict__ in,
                                                     u16* __restrict__ out, int n8){
  int i = blockIdx.x * 256 + threadIdx.x;
  if (i >= n8) return;
  const float4* p = (const float4*)in;
  float4 a = p[2*i], b = p[2*i+1];
  u32x4 o;
  o.x = (unsigned)f2bf(a.x) | ((unsigned)f2bf(a.y) << 16);
  o.y = (unsigned)f2bf(a.z) | ((unsigned)f2bf(a.w) << 16);
  o.z = (unsigned)f2bf(b.x) | ((unsigned)f2bf(b.y) << 16);
  o.w = (unsigned)f2bf(b.z) | ((unsigned)f2bf(b.w) << 16);
  ((u32x4*)out)[i] = o;
}

// all four 1024x1024 weight casts in one launch (y = which)
__global__ __launch_bounds__(256) void cast_w4(const float* __restrict__ Wq,
                                               const float* __restrict__ Wk,
                                               const float* __restrict__ Wv,
                                               const float* __restrict__ Wo,
                                               u16* __restrict__ Wqkv, u16* __restrict__ Wob){
  int which = blockIdx.y;
  const float* src = (which == 0) ? Wq : (which == 1) ? Wk : (which == 2) ? Wv : Wo;
  u16* dst = (which == 3) ? Wob : (Wqkv + (size_t)which * HID * HID);
  int i = blockIdx.x * 256 + threadIdx.x;
  const float4* p = (const float4*)src;
  float4 a = p[2*i], b = p[2*i+1];
  u32x4 o;
  o.x = (unsigned)f2bf(a.x) | ((unsigned)f2bf(a.y) << 16);
  o.y = (unsigned)f2bf(a.z) | ((unsigned)f2bf(a.w) << 16);
  o.z = (unsigned)f2bf(b.x) | ((unsigned)f2bf(b.y) << 16);
  o.w = (unsigned)f2bf(b.z) | ((unsigned)f2bf(b.w) << 16);
  ((u32x4*)dst)[i] = o;
}

// GEMM staging (128-row tiles, BK=32): 4 wave-loads per wave per stage
#define STAGE_G(Ag, Bg, k0, buf) do { \
  _Pragma("unroll") \
  for (int i_ = 0; i_ < 2; i_++){ \
    int u_ = (i_*4 + wave) * 64 + lane; \
    int row_ = u_ >> 2, cu_ = u_ & 3; \
    gload16(Ag + (size_t)(m0 + row_) * HID + (k0) + cu_*8, &As[buf][(i_*4 + wave) * 512]); \
    gload16(Bg + (size_t)(n0 + row_) * HID + (k0) + cu_*8, &Bs[buf][(i_*4 + wave) * 512]); \
  } } while(0)

// ---------------- fused QKV GEMM: C = X @ Wqkv^T + bias ----------------
// 2-deep prefetch pipeline: 3 LDS buffers, steady-state s_waitcnt vmcnt(4).
__global__ __launch_bounds__(256) void gemm_qkv(
    const u16* __restrict__ Xb, const u16* __restrict__ Wqkv,
    const float* __restrict__ bq, const float* __restrict__ bk, const float* __restrict__ bv,
    u16* __restrict__ Qb, u16* __restrict__ Kb, u16* __restrict__ Vtb)
{
  __shared__ __attribute__((aligned(16))) u16 As[3][128*32];
  __shared__ __attribute__((aligned(16))) u16 Bs[3][128*32];
  const int tid = threadIdx.x, wave = tid >> 6, lane = tid & 63;
  const int m0 = blockIdx.x * 128, n0 = blockIdx.y * 128;
  const int wr = (wave >> 1) * 64, wc = (wave & 1) * 64;
  const int lr = lane & 15, lg = lane >> 4, kseg = lg * 8;

  f32x4 zero = {0.f, 0.f, 0.f, 0.f};
  f32x4 acc[4][4];
#pragma unroll
  for (int i = 0; i < 4; i++)
#pragma unroll
    for (int j = 0; j < 4; j++) acc[i][j] = zero;

  STAGE_G(Xb, Wqkv, 0, 0);
  STAGE_G(Xb, Wqkv, 32, 1);
  for (int t = 0; t < 32; t++){
    if (t < 31) { asm volatile("s_waitcnt vmcnt(4)" ::: "memory"); }
    else        { asm volatile("s_waitcnt vmcnt(0)" ::: "memory"); }
    __builtin_amdgcn_s_barrier();
    __builtin_amdgcn_sched_barrier(0);
    if (t < 30) STAGE_G(Xb, Wqkv, (t+2)*32, (t+2)%3);
    int cur = t % 3;
    const u16* Ac = As[cur]; const u16* Bc = Bs[cur];
    bf16x8 af[4], bfr[4];
#pragma unroll
    for (int m = 0; m < 4; m++) af[m]  = *(const bf16x8*)&Ac[(wr + m*16 + lr)*32 + kseg];
#pragma unroll
    for (int n = 0; n < 4; n++) bfr[n] = *(const bf16x8*)&Bc[(wc + n*16 + lr)*32 + kseg];
    __builtin_amdgcn_s_setprio(1);
#pragma unroll
    for (int m = 0; m < 4; m++)
#pragma unroll
      for (int n = 0; n < 4; n++)
        acc[m][n] = MFMA16(af[m], bfr[n], acc[m][n]);
    __builtin_amdgcn_s_setprio(0);
  }

  const int sel = n0 >> 10;                       // 0=q 1=k 2=v (tiles never straddle)
  const float* bias = (sel == 0) ? bq : (sel == 1) ? bk : bv;
  // q pre-scaled by 1/sqrt(d) * log2(e) so attention works in exp2 domain
  const float qscale = (sel == 0) ? 0.18033688011f : 1.0f;
#pragma unroll
  for (int n = 0; n < 4; n++){
    int col = n0 + wc + n*16 + lr;
    int o = col & 1023;
    float bb = bias[o];
    int h = o >> 6, d = o & 63;
#pragma unroll
    for (int m = 0; m < 4; m++){
      int rbase = m0 + wr + m*16 + lg*4;
#pragma unroll
      for (int r = 0; r < 4; r++){
        int rowg = rbase + r;
        int b = rowg >> 11, s = rowg & 2047;
        u16 v = f2bf((acc[m][n][r] + bb) * qscale);
        if (sel == 0)      Qb [(((size_t)(b*16 + h))*SEQ + s)*HDIM + d] = v;
        else if (sel == 1) Kb [(((size_t)(b*16 + h))*SEQ + s)*HDIM + d] = v;
        else               Vtb[(((size_t)(b*16 + h))*HDIM + d)*SEQ + s] = v;
      }
    }
  }
}

// ---------------- flash attention ----------------
// 1024 blocks (4/CU), XCD-clustered: each XCD owns 4 heads -> K/V L2-resident.
// Wave = 16 q-rows. Swapped QK^T, exp2 softmax, defer-max, cvt_pk+permlane P,
// double-buffered K/V staging, single raw barrier per tile.
__global__ __launch_bounds__(256) void attn_kernel(
    const u16* __restrict__ Qb, const u16* __restrict__ Kb, const u16* __restrict__ Vtb,
    u16* __restrict__ AOb)
{
  __shared__ __attribute__((aligned(16))) u16 Ks[2][64*64];  // [kv][d] swizzled
  __shared__ __attribute__((aligned(16))) u16 Vs[2][64*64];  // [d][kv] swizzled
  const int tid = threadIdx.x, wave = tid >> 6, lane = tid & 63;
  const int lr = lane & 15, lg = lane >> 4;
  // bijective XCD-cluster swizzle: xcd = bid&7 owns heads 4*xcd..4*xcd+3
  const int bid = blockIdx.x;
  const int xcd = bid & 7, slot = bid >> 3;
  const int bh = xcd*4 + (slot >> 5);
  const int q0 = (slot & 31) * 64;
  const u16* Qh = Qb  + (size_t)bh * SEQ * HDIM;
  const u16* Kh = Kb  + (size_t)bh * SEQ * HDIM;
  const u16* Vh = Vtb + (size_t)bh * HDIM * SEQ;

#define STAGE_KV(kv0, buf) do { \
  _Pragma("unroll") \
  for (int i_ = 0; i_ < 2; i_++){ \
    int u_ = i_*256 + tid; \
    int r_ = u_ >> 3, s_ = u_ & 7, ss_ = s_ ^ (r_ & 7); \
    gload16(Kh + (size_t)((kv0) + r_) * HDIM + ss_*8, &Ks[buf][u_*8]); \
    gload16(Vh + (size_t)r_ * SEQ + (kv0) + ss_*8,    &Vs[buf][u_*8]); \
  } } while(0)

  // Q B-frags (col=q=lr, k=d): qf[ks]
  bf16x8 qf[2];
#pragma unroll
  for (int ks = 0; ks < 2; ks++)
    qf[ks] = *(const bf16x8*)&Qh[(size_t)(q0 + wave*16 + lr) * HDIM + ks*32 + lg*8];

  f32x4 zero = {0.f, 0.f, 0.f, 0.f};
  f32x4 acc[4];
#pragma unroll
  for (int fd = 0; fd < 4; fd++) acc[fd] = zero;
  float m_c = -1e30f;
  float l_c = 0.f;   // per-lane partial sum; cross-lane reduced once at end

  STAGE_KV(0, 0);
  for (int t = 0; t < 32; t++){
    int cur = t & 1;
    asm volatile("s_waitcnt vmcnt(0)" ::: "memory");
    __builtin_amdgcn_s_barrier();
    __builtin_amdgcn_sched_barrier(0);
    if (t < 31) STAGE_KV((t+1)*64, cur ^ 1);
    const u16* Kc = &Ks[cur][0];
    const u16* Vc = &Vs[cur][0];

    // S^T = K Q^T (log2 domain): col=lr=q, row=lg*4+r=kv within block f
    f32x4 st[4];
    __builtin_amdgcn_s_setprio(1);
#pragma unroll
    for (int f = 0; f < 4; f++){
      bf16x8 kf0 = *(const bf16x8*)&Kc[(f*16 + lr)*64 + ((lg     ^ (lr & 7)) * 8)];
      bf16x8 kf1 = *(const bf16x8*)&Kc[(f*16 + lr)*64 + (((4+lg) ^ (lr & 7)) * 8)];
      st[f] = MFMA16(kf0, qf[0], zero);
      st[f] = MFMA16(kf1, qf[1], st[f]);
    }
    __builtin_amdgcn_s_setprio(0);

    // in-lane max over 16 values
    float a0 = fmaxf(fmaxf(st[0][0], st[0][1]), fmaxf(st[0][2], st[0][3]));
    float a1 = fmaxf(fmaxf(st[1][0], st[1][1]), fmaxf(st[1][2], st[1][3]));
    float a2 = fmaxf(fmaxf(st[2][0], st[2][1]), fmaxf(st[2][2], st[2][3]));
    float a3 = fmaxf(fmaxf(st[3][0], st[3][1]), fmaxf(st[3][2], st[3][3]));
    float pm = fmaxf(fmaxf(a0, a1), fmaxf(a2, a3));
    // defer-max (THR=11.5 log2 units): steady state skips reduce+rescale
    if (__any(pm > m_c + 11.5f)){
      float mt = pm;
      mt = fmaxf(mt, __shfl_xor(mt, 16));
      mt = fmaxf(mt, __shfl_xor(mt, 32));
      float mn = fmaxf(m_c, mt);
      float al = __builtin_amdgcn_exp2f(m_c - mn);
      m_c = mn;
      l_c *= al;
      float r0 = __shfl(al, lg*4 + 0), r1 = __shfl(al, lg*4 + 1);
      float r2 = __shfl(al, lg*4 + 2), r3 = __shfl(al, lg*4 + 3);
#pragma unroll
      for (int fd = 0; fd < 4; fd++){
        acc[fd][0] *= r0; acc[fd][1] *= r1;
        acc[fd][2] *= r2; acc[fd][3] *= r3;
      }
    }

    // P = exp2(S - m); pack bf16 pairs; permlane-swap into PV A-frag layout
    unsigned w[4][2];
    float ssum = 0.f;
#pragma unroll
    for (int f = 0; f < 4; f++){
      float p0 = __builtin_amdgcn_exp2f(st[f][0] - m_c);
      float p1 = __builtin_amdgcn_exp2f(st[f][1] - m_c);
      float p2 = __builtin_amdgcn_exp2f(st[f][2] - m_c);
      float p3 = __builtin_amdgcn_exp2f(st[f][3] - m_c);
      ssum += (p0 + p1) + (p2 + p3);
      asm("v_cvt_pk_bf16_f32 %0, %1, %2" : "=v"(w[f][0]) : "v"(p0), "v"(p1));
      asm("v_cvt_pk_bf16_f32 %0, %1, %2" : "=v"(w[f][1]) : "v"(p2), "v"(p3));
    }
    l_c += ssum;
    bf16x8 pa[2];
#pragma unroll
    for (int ks = 0; ks < 2; ks++){
      u32x4 aw;
#pragma unroll
      for (int rr = 0; rr < 2; rr++){
        unsigned X = w[2*ks][rr], Y = w[2*ks+1][rr];
        asm("v_permlane32_swap_b32 %0, %1" : "+v"(X), "+v"(Y));
        asm("v_permlane16_swap_b32 %0, %1" : "+v"(X), "+v"(Y));
        aw[rr] = X; aw[2 + rr] = Y;
      }
      pa[ks] = __builtin_bit_cast(bf16x8, aw);
    }

    // PV: A=P[q][kv] (reg frags), B=V^T[d][kv] -> acc[q][d]
    __builtin_amdgcn_s_setprio(1);
#pragma unroll
    for (int ks = 0; ks < 2; ks++)
#pragma unroll
      for (int fd = 0; fd < 4; fd++){
        bf16x8 vf = *(const bf16x8*)&Vc[(fd*16 + lr)*64 + (((ks*4 + lg) ^ (lr & 7)) * 8)];
        acc[fd] = MFMA16(pa[ks], vf, acc[fd]);
      }
    __builtin_amdgcn_s_setprio(0);
  }

  // epilogue: reduce l across lane groups once; AOb[b][s][h*64+d] bf16
  const int b = bh >> 4, h = bh & 15;
  float lt = l_c;
  lt += __shfl_xor(lt, 16);
  lt += __shfl_xor(lt, 32);
  float li[4];
#pragma unroll
  for (int r = 0; r < 4; r++) li[r] = 1.0f / __shfl(lt, lg*4 + r);
#pragma unroll
  for (int fd = 0; fd < 4; fd++){
    int d = h*64 + fd*16 + lr;
#pragma unroll
    for (int r = 0; r < 4; r++){
      int s = q0 + wave*16 + lg*4 + r;
      AOb[((size_t)(b*SEQ + s))*HID + d] = f2bf(acc[fd][r] * li[r]);
    }
  }
}

// ---------------- output projection: Out = AO @ Wo^T + bo (fp32 out) ----------------
// 64(M)x128(N) tiles -> 512 blocks (2/CU); 2-deep prefetch, vmcnt(3).
__global__ __launch_bounds__(256) void gemm_out(
    const u16* __restrict__ Ab, const u16* __restrict__ Wob,
    const float* __restrict__ bo, float* __restrict__ Out)
{
  __shared__ __attribute__((aligned(16))) u16 As[3][64*32];
  __shared__ __attribute__((aligned(16))) u16 Bs[3][128*32];
  const int tid = threadIdx.x, wave = tid >> 6, lane = tid & 63;
  const int m0 = blockIdx.x * 64, n0 = blockIdx.y * 128;
  const int wr = (wave >> 1) * 32, wc = (wave & 1) * 64;
  const int lr = lane & 15, lg = lane >> 4, kseg = lg * 8;

#define STAGE_O(k0, buf) do { \
  { int u_ = wave*64 + lane; \
    int row_ = u_ >> 2, cu_ = u_ & 3; \
    gload16(Ab + (size_t)(m0 + row_) * HID + (k0) + cu_*8, &As[buf][wave * 512]); } \
  _Pragma("unroll") \
  for (int i_ = 0; i_ < 2; i_++){ \
    int u_ = (i_*4 + wave) * 64 + lane; \
    int row_ = u_ >> 2, cu_ = u_ & 3; \
    gload16(Wob + (size_t)(n0 + row_) * HID + (k0) + cu_*8, &Bs[buf][(i_*4 + wave) * 512]); \
  } } while(0)

  f32x4 zero = {0.f, 0.f, 0.f, 0.f};
  f32x4 acc[2][4];
#pragma unroll
  for (int i = 0; i < 2; i++)
#pragma unroll
    for (int j = 0; j < 4; j++) acc[i][j] = zero;

  STAGE_O(0, 0);
  STAGE_O(32, 1);
  for (int t = 0; t < 32; t++){
    if (t < 31) { asm volatile("s_waitcnt vmcnt(3)" ::: "memory"); }
    else        { asm volatile("s_waitcnt vmcnt(0)" ::: "memory"); }
    __builtin_amdgcn_s_barrier();
    __builtin_amdgcn_sched_barrier(0);
    if (t < 30) STAGE_O((t+2)*32, (t+2)%3);
    int cur = t % 3;
    const u16* Ac = As[cur]; const u16* Bc = Bs[cur];
    bf16x8 af[2], bfr[4];
#pragma unroll
    for (int m = 0; m < 2; m++) af[m]  = *(const bf16x8*)&Ac[(wr + m*16 + lr)*32 + kseg];
#pragma unroll
    for (int n = 0; n < 4; n++) bfr[n] = *(const bf16x8*)&Bc[(wc + n*16 + lr)*32 + kseg];
    __builtin_amdgcn_s_setprio(1);
#pragma unroll
    for (int m = 0; m < 2; m++)
#pragma unroll
      for (int n = 0; n < 4; n++)
        acc[m][n] = MFMA16(af[m], bfr[n], acc[m][n]);
    __builtin_amdgcn_s_setprio(0);
  }

#pragma unroll
  for (int n = 0; n < 4; n++){
    int col = n0 + wc + n*16 + lr;
    float bb = bo[col];
#pragma unroll
    for (int m = 0; m < 2; m++){
      int rbase = m0 + wr + m*16 + lg*4;
#pragma unroll
      for (int r = 0; r < 4; r++)
        Out[(size_t)(rbase + r) * HID + col] = acc[m][n][r] + bb;
    }
  }
}

extern "C" void kernel_launch(void* const* d_in, const int* in_sizes, int n_in,
                              void* d_out, int out_size, void* d_ws, size_t ws_size,
                              hipStream_t stream){
  const float* hs = (const float*)d_in[0];
  const float* Wq = (const float*)d_in[1];
  const float* bq = (const float*)d_in[2];
  const float* Wk = (const float*)d_in[3];
  const float* bk = (const float*)d_in[4];
  const float* Wv = (const float*)d_in[5];
  const float* bv = (const float*)d_in[6];
  const float* Wo = (const float*)d_in[7];
  const float* bo = (const float*)d_in[8];
  float* Out = (float*)d_out;

  u16* Xb   = (u16*)d_ws;                          // 4096x1024
  u16* Wqkv = Xb   + (size_t)MTOK * HID;           // 3072x1024
  u16* Wob  = Wqkv + (size_t)3 * HID * HID;        // 1024x1024
  u16* Qb   = Wob  + (size_t)HID * HID;            // [b][h][s][d] (scaled, log2 domain)
  u16* Kb   = Qb   + (size_t)MTOK * HID;           // [b][h][s][d]
  u16* Vtb  = Kb   + (size_t)MTOK * HID;           // [b][h][d][s]
  u16* AOb  = Vtb  + (size_t)MTOK * HID;           // [b][s][h*d]

  cast_f32_bf16<<<2048, 256, 0, stream>>>(hs, Xb, MTOK * HID / 8);
  cast_w4<<<dim3(HID*HID/8/256, 4), 256, 0, stream>>>(Wq, Wk, Wv, Wo, Wqkv, Wob);

  gemm_qkv<<<dim3(MTOK/128, 3*HID/128), 256, 0, stream>>>(Xb, Wqkv, bq, bk, bv, Qb, Kb, Vtb);
  attn_kernel<<<1024, 256, 0, stream>>>(Qb, Kb, Vtb, AOb);
  gemm_out<<<dim3(MTOK/64, HID/128), 256, 0, stream>>>(AOb, Wob, bo, Out);
}

// Round 5
// 204.700 us; speedup vs baseline: 1.0311x; 1.0311x over previous
//
#include <hip/hip_runtime.h>

typedef unsigned short u16;
typedef __attribute__((ext_vector_type(8))) short bf16x8;
typedef __attribute__((ext_vector_type(4))) float f32x4;
typedef __attribute__((ext_vector_type(4))) unsigned int u32x4;

#define SEQ 2048
#define HID 1024
#define NHEAD 16
#define HDIM 64
#define MTOK 4096  // B*S

#define MFMA16(a,b,c) __builtin_amdgcn_mfma_f32_16x16x32_bf16(a,b,c,0,0,0)

__device__ __forceinline__ u16 f2bf(float f){
  unsigned int u = __builtin_bit_cast(unsigned int, f);
  u += 0x7fffu + ((u >> 16) & 1u);
  return (u16)(u >> 16);
}

__device__ __forceinline__ void gload16(const u16* g, u16* l){
  __builtin_amdgcn_global_load_lds((const __attribute__((address_space(1))) void*)g,
                                   (__attribute__((address_space(3))) void*)l, 16, 0, 0);
}

// ---------------- all casts in one launch: grid (512, 8) ----------------
// y<4: hidden_states quarter y; y>=4: weight (q,k,v,o)
__global__ __launch_bounds__(256) void cast_all(
    const float* __restrict__ hs, const float* __restrict__ Wq,
    const float* __restrict__ Wk, const float* __restrict__ Wv,
    const float* __restrict__ Wo, u16* __restrict__ Xb,
    u16* __restrict__ Wqkv, u16* __restrict__ Wob){
  int y = blockIdx.y;
  int i = blockIdx.x * 256 + threadIdx.x;
  const float* src; u16* dst; size_t i8;
  if (y < 4){ src = hs; dst = Xb; i8 = (size_t)y * 131072 + i; }
  else {
    int w = y - 4;
    src = (w == 0) ? Wq : (w == 1) ? Wk : (w == 2) ? Wv : Wo;
    dst = (w == 3) ? Wob : (Wqkv + (size_t)w * HID * HID);
    i8 = i;
  }
  const float4* p = (const float4*)src;
  float4 a = p[2*i8], b = p[2*i8+1];
  u32x4 o;
  o.x = (unsigned)f2bf(a.x) | ((unsigned)f2bf(a.y) << 16);
  o.y = (unsigned)f2bf(a.z) | ((unsigned)f2bf(a.w) << 16);
  o.z = (unsigned)f2bf(b.x) | ((unsigned)f2bf(b.y) << 16);
  o.w = (unsigned)f2bf(b.z) | ((unsigned)f2bf(b.w) << 16);
  ((u32x4*)dst)[i8] = o;
}

// ---------------- fused QKV GEMM: C = X @ Wqkv^T + bias ----------------
// 2-deep prefetch (3 bufs, vmcnt(4)); epilogue via LDS transpose -> coalesced stores.
__global__ __launch_bounds__(256) void gemm_qkv(
    const u16* __restrict__ Xb, const u16* __restrict__ Wqkv,
    const float* __restrict__ bq, const float* __restrict__ bk, const float* __restrict__ bv,
    u16* __restrict__ Qb, u16* __restrict__ Kb, u16* __restrict__ Vtb)
{
  // pool: staging As(3x4096)@0, Bs(3x4096)@12288; epilogue Ct[128][136]@0
  __shared__ __attribute__((aligned(16))) u16 pool[24576];
  u16* const AsP = pool;
  u16* const BsP = pool + 12288;
  const int tid = threadIdx.x, wave = tid >> 6, lane = tid & 63;
  const int m0 = blockIdx.x * 128, n0 = blockIdx.y * 128;
  const int wr = (wave >> 1) * 64, wc = (wave & 1) * 64;
  const int lr = lane & 15, lg = lane >> 4, kseg = lg * 8;

#define STAGE_Q(k0, buf) do { \
  _Pragma("unroll") \
  for (int i_ = 0; i_ < 2; i_++){ \
    int u_ = (i_*4 + wave) * 64 + lane; \
    int row_ = u_ >> 2, cu_ = u_ & 3; \
    gload16(Xb   + (size_t)(m0 + row_) * HID + (k0) + cu_*8, AsP + (buf)*4096 + (i_*4 + wave) * 512); \
    gload16(Wqkv + (size_t)(n0 + row_) * HID + (k0) + cu_*8, BsP + (buf)*4096 + (i_*4 + wave) * 512); \
  } } while(0)

  f32x4 zero = {0.f, 0.f, 0.f, 0.f};
  f32x4 acc[4][4];
#pragma unroll
  for (int i = 0; i < 4; i++)
#pragma unroll
    for (int j = 0; j < 4; j++) acc[i][j] = zero;

  STAGE_Q(0, 0);
  STAGE_Q(32, 1);
  for (int t = 0; t < 32; t++){
    if (t < 31) { asm volatile("s_waitcnt vmcnt(4)" ::: "memory"); }
    else        { asm volatile("s_waitcnt vmcnt(0)" ::: "memory"); }
    __builtin_amdgcn_s_barrier();
    __builtin_amdgcn_sched_barrier(0);
    if (t < 30) STAGE_Q((t+2)*32, (t+2)%3);
    int cur = t % 3;
    const u16* Ac = AsP + cur*4096; const u16* Bc = BsP + cur*4096;
    bf16x8 af[4], bfr[4];
#pragma unroll
    for (int m = 0; m < 4; m++) af[m]  = *(const bf16x8*)&Ac[(wr + m*16 + lr)*32 + kseg];
#pragma unroll
    for (int n = 0; n < 4; n++) bfr[n] = *(const bf16x8*)&Bc[(wc + n*16 + lr)*32 + kseg];
    __builtin_amdgcn_s_setprio(1);
#pragma unroll
    for (int m = 0; m < 4; m++)
#pragma unroll
      for (int n = 0; n < 4; n++)
        acc[m][n] = MFMA16(af[m], bfr[n], acc[m][n]);
    __builtin_amdgcn_s_setprio(0);
  }

  // ---- epilogue: bias+scale -> bf16 -> LDS (V transposed) -> coalesced 128B stores
  __syncthreads();                                 // staging pool dead, reuse as Ct
  const int sel = n0 >> 10;                        // 0=q 1=k 2=v
  const float* bias = (sel == 0) ? bq : (sel == 1) ? bk : bv;
  const float qscale = (sel == 0) ? 0.18033688011f : 1.0f;  // 1/8 * log2(e)
  u16* const Ct = pool;                            // [128][136]
#pragma unroll
  for (int n = 0; n < 4; n++){
    int colL = wc + n*16 + lr;
    float bb = bias[(n0 + colL) & 1023];
#pragma unroll
    for (int m = 0; m < 4; m++){
      int rowL = wr + m*16 + lg*4;
#pragma unroll
      for (int r = 0; r < 4; r++){
        u16 v = f2bf((acc[m][n][r] + bb) * qscale);
        if (sel == 2) Ct[(size_t)colL*136 + rowL + r] = v;
        else          Ct[(size_t)(rowL + r)*136 + colL] = v;
      }
    }
  }
  __syncthreads();
  const int hbase = (n0 & 1023) >> 6;
  if (sel < 2){
    int sl = tid & 127, hh = tid >> 7;
    int rowg = m0 + sl, b = rowg >> 11, s = rowg & 2047;
    u16* dst = ((sel == 0) ? Qb : Kb) + (((size_t)(b*16 + hbase + hh))*SEQ + s)*HDIM;
    const u16* srcl = Ct + (size_t)sl*136 + hh*64;
#pragma unroll
    for (int j = 0; j < 8; j++)
      *(u32x4*)(dst + j*8) = *(const u32x4*)(srcl + j*8);
  } else {
    int dcol = tid >> 1, sh = tid & 1;
    int b = m0 >> 11, s0 = (m0 & 2047) + sh*64;
    int h = hbase + (dcol >> 6), d = dcol & 63;
    u16* dst = Vtb + (((size_t)(b*16 + h))*HDIM + d)*SEQ + s0;
    const u16* srcl = Ct + (size_t)dcol*136 + sh*64;
#pragma unroll
    for (int j = 0; j < 8; j++)
      *(u32x4*)(dst + j*8) = *(const u32x4*)(srcl + j*8);
  }
}

// ---------------- flash attention ----------------
// grid 512 (XCD-clustered: xcd owns 4 heads). 4 waves x 32 q-rows (qb=2), KV tiles 64,
// 2-deep staging (3 bufs, vmcnt(4)). Swapped QK^T, exp2 softmax, defer-max,
// cvt_pk+permlane P->A-frag (no LDS round-trip).
__global__ __launch_bounds__(256) void attn_kernel(
    const u16* __restrict__ Qb, const u16* __restrict__ Kb, const u16* __restrict__ Vtb,
    u16* __restrict__ AOb)
{
  __shared__ __attribute__((aligned(16))) u16 Ks[3][64*64];  // [kv][d] swizzled
  __shared__ __attribute__((aligned(16))) u16 Vs[3][64*64];  // [d][kv] swizzled
  const int tid = threadIdx.x, wave = tid >> 6, lane = tid & 63;
  const int lr = lane & 15, lg = lane >> 4;
  // bijective XCD-cluster swizzle: xcd = bid&7 owns heads 4*xcd..4*xcd+3
  const int bid = blockIdx.x;
  const int xcd = bid & 7, slot = bid >> 3;
  const int bh = xcd*4 + (slot >> 4);
  const int q0 = (slot & 15) * 128;
  const u16* Qh = Qb  + (size_t)bh * SEQ * HDIM;
  const u16* Kh = Kb  + (size_t)bh * SEQ * HDIM;
  const u16* Vh = Vtb + (size_t)bh * HDIM * SEQ;

#define STAGE_KV(kv0, buf) do { \
  _Pragma("unroll") \
  for (int i_ = 0; i_ < 2; i_++){ \
    int u_ = i_*256 + tid; \
    int r_ = u_ >> 3, s_ = u_ & 7, ss_ = s_ ^ (r_ & 7); \
    gload16(Kh + (size_t)((kv0) + r_) * HDIM + ss_*8, &Ks[buf][u_*8]); \
    gload16(Vh + (size_t)r_ * SEQ + (kv0) + ss_*8,    &Vs[buf][u_*8]); \
  } } while(0)

  // Q B-frags (col=q=lr, k=d): qf[qb][ks]
  bf16x8 qf[2][2];
#pragma unroll
  for (int qb = 0; qb < 2; qb++)
#pragma unroll
    for (int ks = 0; ks < 2; ks++)
      qf[qb][ks] = *(const bf16x8*)&Qh[(size_t)(q0 + wave*32 + qb*16 + lr) * HDIM + ks*32 + lg*8];

  f32x4 zero = {0.f, 0.f, 0.f, 0.f};
  f32x4 acc[2][4];
#pragma unroll
  for (int qb = 0; qb < 2; qb++)
#pragma unroll
    for (int fd = 0; fd < 4; fd++) acc[qb][fd] = zero;
  float m_c[2] = {-1e30f, -1e30f};
  float l_c[2] = {0.f, 0.f};   // per-lane partials; reduced once at end

  STAGE_KV(0, 0);
  STAGE_KV(64, 1);
  for (int t = 0; t < 32; t++){
    if (t < 31) { asm volatile("s_waitcnt vmcnt(4)" ::: "memory"); }
    else        { asm volatile("s_waitcnt vmcnt(0)" ::: "memory"); }
    __builtin_amdgcn_s_barrier();
    __builtin_amdgcn_sched_barrier(0);
    if (t < 30) STAGE_KV((t+2)*64, (t+2)%3);
    int cur = t % 3;
    const u16* Kc = &Ks[cur][0];
    const u16* Vc = &Vs[cur][0];

    // S^T = K Q^T (log2 domain): col=lr=q, row=lg*4+r=kv within block f
    f32x4 st[2][4];
    __builtin_amdgcn_s_setprio(1);
#pragma unroll
    for (int f = 0; f < 4; f++){
      bf16x8 kf0 = *(const bf16x8*)&Kc[(f*16 + lr)*64 + ((lg     ^ (lr & 7)) * 8)];
      bf16x8 kf1 = *(const bf16x8*)&Kc[(f*16 + lr)*64 + (((4+lg) ^ (lr & 7)) * 8)];
      st[0][f] = MFMA16(kf0, qf[0][0], zero);
      st[0][f] = MFMA16(kf1, qf[0][1], st[0][f]);
      st[1][f] = MFMA16(kf0, qf[1][0], zero);
      st[1][f] = MFMA16(kf1, qf[1][1], st[1][f]);
    }
    __builtin_amdgcn_s_setprio(0);

    // in-lane max over 16 kv values per qb
    float pm[2];
#pragma unroll
    for (int qb = 0; qb < 2; qb++){
      float a0 = fmaxf(fmaxf(st[qb][0][0], st[qb][0][1]), fmaxf(st[qb][0][2], st[qb][0][3]));
      float a1 = fmaxf(fmaxf(st[qb][1][0], st[qb][1][1]), fmaxf(st[qb][1][2], st[qb][1][3]));
      float a2 = fmaxf(fmaxf(st[qb][2][0], st[qb][2][1]), fmaxf(st[qb][2][2], st[qb][2][3]));
      float a3 = fmaxf(fmaxf(st[qb][3][0], st[qb][3][1]), fmaxf(st[qb][3][2], st[qb][3][3]));
      pm[qb] = fmaxf(fmaxf(a0, a1), fmaxf(a2, a3));
    }
    // defer-max (THR=11.5 log2 units)
    int need = (pm[0] > m_c[0] + 11.5f) || (pm[1] > m_c[1] + 11.5f);
    if (__any(need)){
#pragma unroll
      for (int qb = 0; qb < 2; qb++){
        float mt = pm[qb];
        mt = fmaxf(mt, __shfl_xor(mt, 16));
        mt = fmaxf(mt, __shfl_xor(mt, 32));
        float mn = fmaxf(m_c[qb], mt);
        float al = __builtin_amdgcn_exp2f(m_c[qb] - mn);
        m_c[qb] = mn;
        l_c[qb] *= al;
        float r0 = __shfl(al, lg*4 + 0), r1 = __shfl(al, lg*4 + 1);
        float r2 = __shfl(al, lg*4 + 2), r3 = __shfl(al, lg*4 + 3);
#pragma unroll
        for (int fd = 0; fd < 4; fd++){
          acc[qb][fd][0] *= r0; acc[qb][fd][1] *= r1;
          acc[qb][fd][2] *= r2; acc[qb][fd][3] *= r3;
        }
      }
    }

    // P = exp2(S - m); pack bf16; permlane-swap into PV A-frag layout
    bf16x8 pa[2][2];
#pragma unroll
    for (int qb = 0; qb < 2; qb++){
      unsigned w[4][2];
      float ssum = 0.f;
#pragma unroll
      for (int f = 0; f < 4; f++){
        float p0 = __builtin_amdgcn_exp2f(st[qb][f][0] - m_c[qb]);
        float p1 = __builtin_amdgcn_exp2f(st[qb][f][1] - m_c[qb]);
        float p2 = __builtin_amdgcn_exp2f(st[qb][f][2] - m_c[qb]);
        float p3 = __builtin_amdgcn_exp2f(st[qb][f][3] - m_c[qb]);
        ssum += (p0 + p1) + (p2 + p3);
        asm("v_cvt_pk_bf16_f32 %0, %1, %2" : "=v"(w[f][0]) : "v"(p0), "v"(p1));
        asm("v_cvt_pk_bf16_f32 %0, %1, %2" : "=v"(w[f][1]) : "v"(p2), "v"(p3));
      }
      l_c[qb] += ssum;
#pragma unroll
      for (int ks = 0; ks < 2; ks++){
        u32x4 aw;
#pragma unroll
        for (int rr = 0; rr < 2; rr++){
          unsigned X = w[2*ks][rr], Y = w[2*ks+1][rr];
          asm("v_permlane32_swap_b32 %0, %1" : "+v"(X), "+v"(Y));
          asm("v_permlane16_swap_b32 %0, %1" : "+v"(X), "+v"(Y));
          aw[rr] = X; aw[2 + rr] = Y;
        }
        pa[qb][ks] = __builtin_bit_cast(bf16x8, aw);
      }
    }

    // PV: A=P[q][kv] (reg), B=V^T[d][kv] -> acc[q][d]
    __builtin_amdgcn_s_setprio(1);
#pragma unroll
    for (int ks = 0; ks < 2; ks++)
#pragma unroll
      for (int fd = 0; fd < 4; fd++){
        bf16x8 vf = *(const bf16x8*)&Vc[(fd*16 + lr)*64 + (((ks*4 + lg) ^ (lr & 7)) * 8)];
        acc[0][fd] = MFMA16(pa[0][ks], vf, acc[0][fd]);
        acc[1][fd] = MFMA16(pa[1][ks], vf, acc[1][fd]);
      }
    __builtin_amdgcn_s_setprio(0);
  }

  // epilogue: reduce l once; AOb[b][s][h*64+d] bf16
  const int b = bh >> 4, h = bh & 15;
#pragma unroll
  for (int qb = 0; qb < 2; qb++){
    float lt = l_c[qb];
    lt += __shfl_xor(lt, 16);
    lt += __shfl_xor(lt, 32);
    float li[4];
#pragma unroll
    for (int r = 0; r < 4; r++) li[r] = 1.0f / __shfl(lt, lg*4 + r);
#pragma unroll
    for (int fd = 0; fd < 4; fd++){
      int d = h*64 + fd*16 + lr;
#pragma unroll
      for (int r = 0; r < 4; r++){
        int s = q0 + wave*32 + qb*16 + lg*4 + r;
        AOb[((size_t)(b*SEQ + s))*HID + d] = f2bf(acc[qb][fd][r] * li[r]);
      }
    }
  }
}

// ---------------- output projection: Out = AO @ Wo^T + bo (fp32 out) ----------------
// 64(M)x128(N) tiles -> 512 blocks (2/CU); 2-deep prefetch, vmcnt(3).
__global__ __launch_bounds__(256) void gemm_out(
    const u16* __restrict__ Ab, const u16* __restrict__ Wob,
    const float* __restrict__ bo, float* __restrict__ Out)
{
  __shared__ __attribute__((aligned(16))) u16 As[3][64*32];
  __shared__ __attribute__((aligned(16))) u16 Bs[3][128*32];
  const int tid = threadIdx.x, wave = tid >> 6, lane = tid & 63;
  const int m0 = blockIdx.x * 64, n0 = blockIdx.y * 128;
  const int wr = (wave >> 1) * 32, wc = (wave & 1) * 64;
  const int lr = lane & 15, lg = lane >> 4, kseg = lg * 8;

#define STAGE_O(k0, buf) do { \
  { int u_ = wave*64 + lane; \
    int row_ = u_ >> 2, cu_ = u_ & 3; \
    gload16(Ab + (size_t)(m0 + row_) * HID + (k0) + cu_*8, &As[buf][wave * 512]); } \
  _Pragma("unroll") \
  for (int i_ = 0; i_ < 2; i_++){ \
    int u_ = (i_*4 + wave) * 64 + lane; \
    int row_ = u_ >> 2, cu_ = u_ & 3; \
    gload16(Wob + (size_t)(n0 + row_) * HID + (k0) + cu_*8, &Bs[buf][(i_*4 + wave) * 512]); \
  } } while(0)

  f32x4 zero = {0.f, 0.f, 0.f, 0.f};
  f32x4 acc[2][4];
#pragma unroll
  for (int i = 0; i < 2; i++)
#pragma unroll
    for (int j = 0; j < 4; j++) acc[i][j] = zero;

  STAGE_O(0, 0);
  STAGE_O(32, 1);
  for (int t = 0; t < 32; t++){
    if (t < 31) { asm volatile("s_waitcnt vmcnt(3)" ::: "memory"); }
    else        { asm volatile("s_waitcnt vmcnt(0)" ::: "memory"); }
    __builtin_amdgcn_s_barrier();
    __builtin_amdgcn_sched_barrier(0);
    if (t < 30) STAGE_O((t+2)*32, (t+2)%3);
    int cur = t % 3;
    const u16* Ac = As[cur]; const u16* Bc = Bs[cur];
    bf16x8 af[2], bfr[4];
#pragma unroll
    for (int m = 0; m < 2; m++) af[m]  = *(const bf16x8*)&Ac[(wr + m*16 + lr)*32 + kseg];
#pragma unroll
    for (int n = 0; n < 4; n++) bfr[n] = *(const bf16x8*)&Bc[(wc + n*16 + lr)*32 + kseg];
    __builtin_amdgcn_s_setprio(1);
#pragma unroll
    for (int m = 0; m < 2; m++)
#pragma unroll
      for (int n = 0; n < 4; n++)
        acc[m][n] = MFMA16(af[m], bfr[n], acc[m][n]);
    __builtin_amdgcn_s_setprio(0);
  }

#pragma unroll
  for (int n = 0; n < 4; n++){
    int col = n0 + wc + n*16 + lr;
    float bb = bo[col];
#pragma unroll
    for (int m = 0; m < 2; m++){
      int rbase = m0 + wr + m*16 + lg*4;
#pragma unroll
      for (int r = 0; r < 4; r++)
        Out[(size_t)(rbase + r) * HID + col] = acc[m][n][r] + bb;
    }
  }
}

extern "C" void kernel_launch(void* const* d_in, const int* in_sizes, int n_in,
                              void* d_out, int out_size, void* d_ws, size_t ws_size,
                              hipStream_t stream){
  const float* hs = (const float*)d_in[0];
  const float* Wq = (const float*)d_in[1];
  const float* bq = (const float*)d_in[2];
  const float* Wk = (const float*)d_in[3];
  const float* bk = (const float*)d_in[4];
  const float* Wv = (const float*)d_in[5];
  const float* bv = (const float*)d_in[6];
  const float* Wo = (const float*)d_in[7];
  const float* bo = (const float*)d_in[8];
  float* Out = (float*)d_out;

  u16* Xb   = (u16*)d_ws;                          // 4096x1024
  u16* Wqkv = Xb   + (size_t)MTOK * HID;           // 3072x1024
  u16* Wob  = Wqkv + (size_t)3 * HID * HID;        // 1024x1024
  u16* Qb   = Wob  + (size_t)HID * HID;            // [b][h][s][d] (scaled, log2 domain)
  u16* Kb   = Qb   + (size_t)MTOK * HID;           // [b][h][s][d]
  u16* Vtb  = Kb   + (size_t)MTOK * HID;           // [b][h][d][s]
  u16* AOb  = Vtb  + (size_t)MTOK * HID;           // [b][s][h*d]

  cast_all<<<dim3(512, 8), 256, 0, stream>>>(hs, Wq, Wk, Wv, Wo, Xb, Wqkv, Wob);
  gemm_qkv<<<dim3(MTOK/128, 3*HID/128), 256, 0, stream>>>(Xb, Wqkv, bq, bk, bv, Qb, Kb, Vtb);
  attn_kernel<<<512, 256, 0, stream>>>(Qb, Kb, Vtb, AOb);
  gemm_out<<<dim3(MTOK/64, HID/128), 256, 0, stream>>>(AOb, Wob, bo, Out);
}